// Round 1
// baseline (1005.920 us; speedup 1.0000x reference)
//
#include <hip/hip_runtime.h>
#include <math.h>

#define CCH   50
#define HH    256
#define WW    256
#define BATCH 16
#define HSZ   64
#define WSZ   64
#define NTOP  240

// ---------------- Kernel 1: conv3x3 (50->50) + ReLU ----------------
__global__ __launch_bounds__(256) void conv1_relu_k(
    const float* __restrict__ in, const float* __restrict__ w1,
    const float* __restrict__ b1, float* __restrict__ x1) {
  int idx = blockIdx.x * 256 + threadIdx.x;      // b*65536 + h*256 + w
  int b = idx >> 16, hw = idx & 65535;
  int h = hw >> 8, w = hw & 255;
  const float* ip = in + (size_t)b * CCH * 65536 + hw;

  float acc[CCH];
#pragma unroll
  for (int co = 0; co < CCH; ++co) acc[co] = b1[co];

  bool hm = h > 0, hp = h < HH - 1, wm = w > 0, wp = w < WW - 1;

  for (int ci = 0; ci < CCH; ++ci) {
    const float* p = ip + (size_t)ci * 65536;
    float v0 = (hm && wm) ? p[-257] : 0.f;
    float v1 = hm         ? p[-256] : 0.f;
    float v2 = (hm && wp) ? p[-255] : 0.f;
    float v3 = wm         ? p[-1]   : 0.f;
    float v4 =              p[0];
    float v5 = wp         ? p[1]    : 0.f;
    float v6 = (hp && wm) ? p[255]  : 0.f;
    float v7 = hp         ? p[256]  : 0.f;
    float v8 = (hp && wp) ? p[257]  : 0.f;
    const float* wr = w1 + ci * 9;               // + co*450 below
#pragma unroll
    for (int co = 0; co < CCH; ++co) {
      const float* wk9 = wr + co * (CCH * 9);
      float a = acc[co];
      a = fmaf(wk9[0], v0, a); a = fmaf(wk9[1], v1, a); a = fmaf(wk9[2], v2, a);
      a = fmaf(wk9[3], v3, a); a = fmaf(wk9[4], v4, a); a = fmaf(wk9[5], v5, a);
      a = fmaf(wk9[6], v6, a); a = fmaf(wk9[7], v7, a); a = fmaf(wk9[8], v8, a);
      acc[co] = a;
    }
  }
  float* op = x1 + (size_t)b * CCH * 65536 + hw;
#pragma unroll
  for (int co = 0; co < CCH; ++co) op[(size_t)co * 65536] = fmaxf(acc[co], 0.f);
}

// ---------------- Kernel 2: conv3x3 (50->2) + softmax[:,1] ----------------
__global__ __launch_bounds__(256) void conv2_softmax_k(
    const float* __restrict__ x1, const float* __restrict__ w2,
    const float* __restrict__ b2, float* __restrict__ sm) {
  int idx = blockIdx.x * 256 + threadIdx.x;
  int b = idx >> 16, hw = idx & 65535;
  int h = hw >> 8, w = hw & 255;
  const float* ip = x1 + (size_t)b * CCH * 65536 + hw;

  float a0 = b2[0], a1 = b2[1];
  bool hm = h > 0, hp = h < HH - 1, wm = w > 0, wp = w < WW - 1;

  for (int ci = 0; ci < CCH; ++ci) {
    const float* p = ip + (size_t)ci * 65536;
    float v0 = (hm && wm) ? p[-257] : 0.f;
    float v1 = hm         ? p[-256] : 0.f;
    float v2 = (hm && wp) ? p[-255] : 0.f;
    float v3 = wm         ? p[-1]   : 0.f;
    float v4 =              p[0];
    float v5 = wp         ? p[1]    : 0.f;
    float v6 = (hp && wm) ? p[255]  : 0.f;
    float v7 = hp         ? p[256]  : 0.f;
    float v8 = (hp && wp) ? p[257]  : 0.f;
    const float* q0 = w2 + ci * 9;
    const float* q1 = w2 + CCH * 9 + ci * 9;
    a0 = fmaf(q0[0], v0, a0); a0 = fmaf(q0[1], v1, a0); a0 = fmaf(q0[2], v2, a0);
    a0 = fmaf(q0[3], v3, a0); a0 = fmaf(q0[4], v4, a0); a0 = fmaf(q0[5], v5, a0);
    a0 = fmaf(q0[6], v6, a0); a0 = fmaf(q0[7], v7, a0); a0 = fmaf(q0[8], v8, a0);
    a1 = fmaf(q1[0], v0, a1); a1 = fmaf(q1[1], v1, a1); a1 = fmaf(q1[2], v2, a1);
    a1 = fmaf(q1[3], v3, a1); a1 = fmaf(q1[4], v4, a1); a1 = fmaf(q1[5], v5, a1);
    a1 = fmaf(q1[6], v6, a1); a1 = fmaf(q1[7], v7, a1); a1 = fmaf(q1[8], v8, a1);
  }
  // softmax over {a0,a1}, channel 1 = sigmoid(a1 - a0)
  sm[(size_t)b * 65536 + hw] = 1.f / (1.f + expf(a0 - a1));
}

// ---------------- Kernel 3: 4x4 avg pool + LeakyReLU(0.1) ----------------
__global__ __launch_bounds__(256) void pool_leaky_k(
    const float* __restrict__ sm, float* __restrict__ pool) {
  int idx = blockIdx.x * 256 + threadIdx.x;      // b*4096 + hs*64 + ws
  int b = idx >> 12, hw = idx & 4095;
  int hs = hw >> 6, ws = hw & 63;
  const float* p = sm + (size_t)b * 65536 + hs * 4 * WW + ws * 4;
  float s = 0.f;
#pragma unroll
  for (int r = 0; r < 4; ++r)
#pragma unroll
    for (int c = 0; c < 4; ++c) s += p[r * WW + c];
  s *= (1.f / 16.f);
  pool[idx] = (s >= 0.f) ? s : 0.1f * s;
}

// ---------------- Kernel 4: 25-tap learned mixing -> final_mask ----------------
__global__ __launch_bounds__(256) void mix_mask_k(
    const float* __restrict__ pool, const float* __restrict__ wk,
    const float* __restrict__ bk, float* __restrict__ mask_out) {
  int idx = blockIdx.x * 256 + threadIdx.x;      // b*4096 + hs*64 + ws
  int b = idx >> 12, hw = idx & 4095;
  int hs = hw >> 6, ws = hw & 63;
  float c = pool[idx];
  float s = 0.f;
#pragma unroll
  for (int i = 0; i < 5; ++i) {
#pragma unroll
    for (int j = 0; j < 5; ++j) {
      int y = hs + i - 2, x = ws + j - 2;
      float win = (y >= 0 && y < HSZ && x >= 0 && x < WSZ)
                      ? pool[(size_t)b * 4096 + y * WSZ + x] : 0.f;
      int k = i * 5 + j;
      s += (wk[k] * c + bk[k]) * win;
    }
  }
  mask_out[idx] = s;
}

// ---------------- Kernel 5: per-batch top-240 + ascending index sort ----------------
__global__ __launch_bounds__(256) void topk_sort_k(
    const float* __restrict__ mask, float* __restrict__ ob, float* __restrict__ oh,
    float* __restrict__ ow, int* __restrict__ idx_ws) {
  __shared__ unsigned long long keys[4096];
  __shared__ int sidx[256];
  int b = blockIdx.x, t = threadIdx.x;

  for (int i = t; i < 4096; i += 256) {
    float v = mask[(size_t)b * 4096 + i];
    unsigned u = __float_as_uint(v);
    u = (u & 0x80000000u) ? ~u : (u | 0x80000000u);   // order-preserving map
    u = ~u;                                            // ascending sort -> value desc
    keys[i] = ((unsigned long long)u << 12) | (unsigned)i;  // tie: lower idx first
  }
  __syncthreads();

  // bitonic sort 4096, ascending
  for (int k = 2; k <= 4096; k <<= 1) {
    for (int j = k >> 1; j > 0; j >>= 1) {
      for (int m = t; m < 2048; m += 256) {
        int i = ((m & ~(j - 1)) << 1) | (m & (j - 1));
        int l = i | j;
        bool up = ((i & k) == 0);
        unsigned long long a = keys[i], c = keys[l];
        if ((a > c) == up) { keys[i] = c; keys[l] = a; }
      }
      __syncthreads();
    }
  }

  // first 240 entries are top-k (value desc). Extract indices, sort ascending.
  sidx[t] = (t < NTOP) ? (int)(keys[t] & 0xFFFu) : 0x7FFFFFFF;
  __syncthreads();
  for (int k = 2; k <= 256; k <<= 1) {
    for (int j = k >> 1; j > 0; j >>= 1) {
      if (t < 128) {
        int i = ((t & ~(j - 1)) << 1) | (t & (j - 1));
        int l = i | j;
        bool up = ((i & k) == 0);
        int a = sidx[i], c = sidx[l];
        if ((a > c) == up) { sidx[i] = c; sidx[l] = a; }
      }
      __syncthreads();
    }
  }

  if (t < NTOP) {
    int id = sidx[t];
    int o = b * NTOP + t;
    ob[o] = (float)b;
    oh[o] = (float)(id >> 6);
    ow[o] = (float)(id & 63);
    idx_ws[o] = id;
  }
}

// ---------------- Kernel 6: gather 6x6 patches (pad=1, stride=4) ----------------
__global__ __launch_bounds__(256) void gather_patch_k(
    const float* __restrict__ in, const int* __restrict__ idx_ws,
    float* __restrict__ patches) {
  int p = blockIdx.x;                 // 0 .. B*240-1
  int b = p / NTOP;
  int id = idx_ws[p];
  int h = id >> 6, w = id & 63;
  int y0 = h * 4 - 1, x0 = w * 4 - 1;
  const float* base = in + (size_t)b * CCH * 65536;
  float* op = patches + (size_t)p * (CCH * 36);
  for (int e = threadIdx.x; e < CCH * 36; e += 256) {
    int c = e / 36;
    int r = (e - c * 36) / 6;
    int col = e - c * 36 - r * 6;
    int y = y0 + r, x = x0 + col;
    float v = 0.f;
    if (y >= 0 && y < HH && x >= 0 && x < WW)
      v = base[(size_t)c * 65536 + y * WW + x];
    op[e] = v;
  }
}

extern "C" void kernel_launch(void* const* d_in, const int* in_sizes, int n_in,
                              void* d_out, int out_size, void* d_ws, size_t ws_size,
                              hipStream_t stream) {
  const float* out_lr = (const float*)d_in[0];
  const float* W1 = (const float*)d_in[1];
  const float* b1 = (const float*)d_in[2];
  const float* W2 = (const float*)d_in[3];
  const float* b2 = (const float*)d_in[4];
  const float* Wk = (const float*)d_in[5];
  const float* bk = (const float*)d_in[6];

  // workspace layout
  float* x1   = (float*)d_ws;                 // 16*50*256*256 = 52,428,800
  float* sm   = x1 + (size_t)52428800;        // 16*256*256    =  1,048,576
  float* pool = sm + (size_t)1048576;         // 16*64*64      =     65,536
  int*  idxb  = (int*)(pool + 65536);         // 16*240        =      3,840

  // output layout (float32, concatenated in reference return order)
  float* out    = (float*)d_out;
  float* o_patch = out;                        // 3840*50*36 = 6,912,000
  float* o_b    = out + (size_t)6912000;       // 3840
  float* o_h    = o_b + 3840;                  // 3840
  float* o_w    = o_h + 3840;                  // 3840
  float* o_mask = o_w + 3840;                  // 16*4096 = 65,536

  conv1_relu_k<<<4096, 256, 0, stream>>>(out_lr, W1, b1, x1);
  conv2_softmax_k<<<4096, 256, 0, stream>>>(x1, W2, b2, sm);
  pool_leaky_k<<<256, 256, 0, stream>>>(sm, pool);
  mix_mask_k<<<256, 256, 0, stream>>>(pool, Wk, bk, o_mask);
  topk_sort_k<<<BATCH, 256, 0, stream>>>(o_mask, o_b, o_h, o_w, idxb);
  gather_patch_k<<<BATCH * NTOP, 256, 0, stream>>>(out_lr, idxb, o_patch);
}